// Round 3
// baseline (1788.951 us; speedup 1.0000x reference)
//
#include <hip/hip_runtime.h>

#define DIMF 64

// deg[row[e]] += ew[e]
__global__ __launch_bounds__(256) void k_deg(const int* __restrict__ row,
    const float* __restrict__ ew, float* __restrict__ deg, int E) {
  for (int e = blockIdx.x * 256 + threadIdx.x; e < E; e += gridDim.x * 256)
    atomicAdd(&deg[row[e]], ew[e]);
}

// deg -> dis in place: d>0 ? rsqrt(d) : 0
__global__ __launch_bounds__(256) void k_dis(float* __restrict__ deg, int n) {
  int i = blockIdx.x * 256 + threadIdx.x;
  if (i < n) {
    float d = deg[i];
    deg[i] = (d > 0.f) ? rsqrtf(d) : 0.f;
  }
}

// dst[row[e]*64+lane] += w_e * src[c*64+lane]
//   w_e = NORM ? dis[row]*w[e]*dis[col] : w[e]
//   c   = PERM ? perm[col[e]] : col[e]
// one wave per edge per iteration; gather + scatter both 256B coalesced.
template <bool PERM, bool NORM>
__global__ __launch_bounds__(256) void k_spmm(const int* __restrict__ row,
    const int* __restrict__ col, const float* __restrict__ w,
    const float* __restrict__ dis, const float* __restrict__ src,
    float* __restrict__ dst, const int* __restrict__ perm, int E) {
  int lane = threadIdx.x & 63;
  int wave = (blockIdx.x * 256 + threadIdx.x) >> 6;
  int nwaves = (gridDim.x * 256) >> 6;
  for (int e = wave; e < E; e += nwaves) {
    int r = row[e];
    int c = col[e];
    float we = w[e];
    if (NORM) we *= dis[r] * dis[c];   // broadcast loads, L2-resident
    if (PERM) c = perm[c];
    float v = we * src[(size_t)c * DIMF + lane];
    atomicAdd(&dst[(size_t)r * DIMF + lane], v);
  }
}

// out = a*x + b*S1 + c2*S2   (float4-vectorized)
__global__ __launch_bounds__(256) void k_combine(const float* __restrict__ x,
    const float* __restrict__ s1, const float* __restrict__ s2,
    const float* __restrict__ temp, float* __restrict__ out, int n4) {
  float T0 = fmaxf(temp[0], 0.f);
  float T1 = fmaxf(temp[1], 0.f);
  float T2 = fmaxf(temp[2], 0.f);
  float c2 = (T0 + T2 - 2.f * T1) * 0.25f;
  float a = T1 + c2;                       // c0+c1+c2
  float b = -((T1 - T0) + 2.f * c2);       // -(c1+2c2)
  const float4* x4 = (const float4*)x;
  const float4* a4 = (const float4*)s1;
  const float4* b4 = (const float4*)s2;
  float4* o4 = (float4*)out;
  for (int i = blockIdx.x * 256 + threadIdx.x; i < n4; i += gridDim.x * 256) {
    float4 xv = x4[i], sv = a4[i], tv = b4[i];
    float4 r;
    r.x = a * xv.x + b * sv.x + c2 * tv.x;
    r.y = a * xv.y + b * sv.y + c2 * tv.y;
    r.z = a * xv.z + b * sv.z + c2 * tv.z;
    r.w = a * xv.w + b * sv.w + c2 * tv.w;
    o4[i] = r;
  }
}

extern "C" void kernel_launch(void* const* d_in, const int* in_sizes, int n_in,
                              void* d_out, int out_size, void* d_ws, size_t ws_size,
                              hipStream_t stream) {
  const float* x    = (const float*)d_in[0];
  const int*   shuf = (const int*)d_in[1];
  const int*   eidx = (const int*)d_in[2];
  const float* ew   = (const float*)d_in[3];
  const int*   nidx = (const int*)d_in[4];
  const float* nwt  = (const float*)d_in[5];
  const float* temp = (const float*)d_in[6];

  const int ND = in_sizes[0];        // N*64
  const int n  = ND / DIMF;          // N
  const int E  = in_sizes[2] / 2;    // edges (laplacian)
  const int En = in_sizes[4] / 2;    // edges (neighbor)

  const int* erow = eidx;
  const int* ecol = eidx + E;
  const int* nrow = nidx;
  const int* ncol = nidx + En;

  // workspace: dis (n floats) + S1 (ND floats) = ~26 MB (structural minimum)
  float* dis = (float*)d_ws;         // deg, then dis in place
  float* S1  = dis + n;              // ND floats

  float* out  = (float*)d_out;       // ND
  float* zpos = out + ND;            // ND
  float* zneg = zpos + ND;           // ND  (used as S2 temp during Laplacian)

  const int tb = 256;
  const int gE = (E + tb - 1) / tb;
  const int gN = (n + tb - 1) / tb;
  const int gS = 2048;               // spmm grid (wave-grid-stride)

  // ---- degree -> dis ----
  hipMemsetAsync(dis, 0, (size_t)n * sizeof(float), stream);
  k_deg<<<gE, tb, 0, stream>>>(erow, ew, dis, E);
  k_dis<<<gN, tb, 0, stream>>>(dis, n);

  // ---- S1 = Anorm @ x ; S2(=zneg buf) = Anorm @ S1 ----
  hipMemsetAsync(S1, 0, (size_t)ND * sizeof(float), stream);
  k_spmm<false, true><<<gS, tb, 0, stream>>>(erow, ecol, ew, dis, x, S1, nullptr, E);
  hipMemsetAsync(zneg, 0, (size_t)ND * sizeof(float), stream);
  k_spmm<false, true><<<gS, tb, 0, stream>>>(erow, ecol, ew, dis, S1, zneg, nullptr, E);

  // ---- out = a*x + b*S1 + c2*S2 ----
  k_combine<<<gS, tb, 0, stream>>>(x, S1, zneg, temp, out, ND / 4);

  // ---- z_pos = Nmm(Nmm(out)) ----  (S1 as temp)
  hipMemsetAsync(S1, 0, (size_t)ND * sizeof(float), stream);
  k_spmm<false, false><<<gS, tb, 0, stream>>>(nrow, ncol, nwt, nullptr, out, S1, nullptr, En);
  hipMemsetAsync(zpos, 0, (size_t)ND * sizeof(float), stream);
  k_spmm<false, false><<<gS, tb, 0, stream>>>(nrow, ncol, nwt, nullptr, S1, zpos, nullptr, En);

  // ---- z_neg = Nmm(Nmm(out[shuf])) ----  (S1 as temp; shuffle fused into gather)
  hipMemsetAsync(S1, 0, (size_t)ND * sizeof(float), stream);
  k_spmm<true, false><<<gS, tb, 0, stream>>>(nrow, ncol, nwt, nullptr, out, S1, shuf, En);
  hipMemsetAsync(zneg, 0, (size_t)ND * sizeof(float), stream);
  k_spmm<false, false><<<gS, tb, 0, stream>>>(nrow, ncol, nwt, nullptr, S1, zneg, nullptr, En);
}

// Round 4
// 1495.990 us; speedup vs baseline: 1.1958x; 1.1958x over previous
//
#include <hip/hip_runtime.h>

#define DIMF 64

// ============================ shared small kernels ============================

// deg -> dis in place: d>0 ? rsqrt(d) : 0
__global__ __launch_bounds__(256) void k_dis(float* __restrict__ deg, int n) {
  int i = blockIdx.x * 256 + threadIdx.x;
  if (i < n) {
    float d = deg[i];
    deg[i] = (d > 0.f) ? rsqrtf(d) : 0.f;
  }
}

// out = a*x + b*S1 + c2*S2   (float4-vectorized)
__global__ __launch_bounds__(256) void k_combine(const float* __restrict__ x,
    const float* __restrict__ s1, const float* __restrict__ s2,
    const float* __restrict__ temp, float* __restrict__ out, int n4) {
  float T0 = fmaxf(temp[0], 0.f);
  float T1 = fmaxf(temp[1], 0.f);
  float T2 = fmaxf(temp[2], 0.f);
  float c2 = (T0 + T2 - 2.f * T1) * 0.25f;
  float a = T1 + c2;                       // c0+c1+c2
  float b = -((T1 - T0) + 2.f * c2);       // -(c1+2c2)
  const float4* x4 = (const float4*)x;
  const float4* a4 = (const float4*)s1;
  const float4* b4 = (const float4*)s2;
  float4* o4 = (float4*)out;
  for (int i = blockIdx.x * 256 + threadIdx.x; i < n4; i += gridDim.x * 256) {
    float4 xv = x4[i], sv = a4[i], tv = b4[i];
    float4 r;
    r.x = a * xv.x + b * sv.x + c2 * tv.x;
    r.y = a * xv.y + b * sv.y + c2 * tv.y;
    r.z = a * xv.z + b * sv.z + c2 * tv.z;
    r.w = a * xv.w + b * sv.w + c2 * tv.w;
    o4[i] = r;
  }
}

// ============================ CSR path ============================

// counts[row[e]] += 1; optionally deg[row[e]] += w[e]
template <bool DEG>
__global__ __launch_bounds__(256) void k_hist(const int* __restrict__ row,
    const float* __restrict__ w, int* __restrict__ cnt,
    float* __restrict__ deg, int E) {
  for (int e = blockIdx.x * 256 + threadIdx.x; e < E; e += gridDim.x * 256) {
    int r = row[e];
    atomicAdd(&cnt[r], 1);
    if (DEG) atomicAdd(&deg[r], w[e]);
  }
}

// single-workgroup exclusive scan in place (n up to ~100k)
__global__ __launch_bounds__(1024) void k_scan(int* __restrict__ a, int n) {
  __shared__ int sums[1024];
  int t = threadIdx.x;
  int chunk = (n + 1023) >> 10;
  int lo = t * chunk;
  int hi = lo + chunk; if (hi > n) hi = n; if (lo > n) lo = n;
  int s = 0;
  for (int i = lo; i < hi; ++i) s += a[i];
  sums[t] = s;
  __syncthreads();
  for (int off = 1; off < 1024; off <<= 1) {
    int v = (t >= off) ? sums[t - off] : 0;
    __syncthreads();
    sums[t] += v;
    __syncthreads();
  }
  int run = (t > 0) ? sums[t - 1] : 0;
  for (int i = lo; i < hi; ++i) { int v = a[i]; a[i] = run; run += v; }
}

// scatter edges into CSR order. rowptr holds exclusive starts on entry and
// SHIFTED ends on exit (rowptr[r] = end(r) = start(r+1)).
// If NORM: stored weight = dis[row]*w*dis[col].
template <bool NORM>
__global__ __launch_bounds__(256) void k_permute(const int* __restrict__ row,
    const int* __restrict__ col, const float* __restrict__ w,
    const float* __restrict__ dis, int* __restrict__ rowptr,
    int* __restrict__ colc, float* __restrict__ wc, int E) {
  for (int e = blockIdx.x * 256 + threadIdx.x; e < E; e += gridDim.x * 256) {
    int r = row[e];
    int c = col[e];
    float we = w[e];
    if (NORM) we *= dis[r] * dis[c];
    int p = atomicAdd(&rowptr[r], 1);
    colc[p] = c;
    wc[p] = we;
  }
}

// one wave per row, lane = feature. rend[r] = end(r), start = rend[r-1].
// dst fully written -> no memset needed, no atomics.
template <bool PERM>
__global__ __launch_bounds__(256) void k_spmm_csr(const int* __restrict__ rend,
    const int* __restrict__ colc, const float* __restrict__ wc,
    const float* __restrict__ src, float* __restrict__ dst,
    const int* __restrict__ perm, int n) {
  int lane = threadIdx.x & 63;
  int wave = (blockIdx.x * 256 + threadIdx.x) >> 6;
  int nw = (gridDim.x * 256) >> 6;
  for (int r = wave; r < n; r += nw) {
    int s = (r > 0) ? rend[r - 1] : 0;
    int e = rend[r];
    float acc = 0.f;
    for (int j = s; j < e; ++j) {
      int c = colc[j];
      if (PERM) c = perm[c];
      acc += wc[j] * src[(size_t)c * DIMF + lane];
    }
    dst[(size_t)r * DIMF + lane] = acc;
  }
}

// ============================ atomic fallback path ============================

template <bool PERM, bool NORM>
__global__ __launch_bounds__(256) void k_spmm_atomic(const int* __restrict__ row,
    const int* __restrict__ col, const float* __restrict__ w,
    const float* __restrict__ dis, const float* __restrict__ src,
    float* __restrict__ dst, const int* __restrict__ perm, int E) {
  int lane = threadIdx.x & 63;
  int wave = (blockIdx.x * 256 + threadIdx.x) >> 6;
  int nwaves = (gridDim.x * 256) >> 6;
  for (int e = wave; e < E; e += nwaves) {
    int r = row[e];
    int c = col[e];
    float we = w[e];
    if (NORM) we *= dis[r] * dis[c];
    if (PERM) c = perm[c];
    float v = we * src[(size_t)c * DIMF + lane];
    atomicAdd(&dst[(size_t)r * DIMF + lane], v);
  }
}

__global__ __launch_bounds__(256) void k_deg(const int* __restrict__ row,
    const float* __restrict__ ew, float* __restrict__ deg, int E) {
  for (int e = blockIdx.x * 256 + threadIdx.x; e < E; e += gridDim.x * 256)
    atomicAdd(&deg[row[e]], ew[e]);
}

// ============================ launch ============================

extern "C" void kernel_launch(void* const* d_in, const int* in_sizes, int n_in,
                              void* d_out, int out_size, void* d_ws, size_t ws_size,
                              hipStream_t stream) {
  const float* x    = (const float*)d_in[0];
  const int*   shuf = (const int*)d_in[1];
  const int*   eidx = (const int*)d_in[2];
  const float* ew   = (const float*)d_in[3];
  const int*   nidx = (const int*)d_in[4];
  const float* nwt  = (const float*)d_in[5];
  const float* temp = (const float*)d_in[6];

  const int ND = in_sizes[0];        // N*64
  const int n  = ND / DIMF;          // N
  const int E  = in_sizes[2] / 2;    // edges (laplacian)
  const int En = in_sizes[4] / 2;    // edges (neighbor)

  const int* erow = eidx;
  const int* ecol = eidx + E;
  const int* nrow = nidx;
  const int* ncol = nidx + En;

  float* out  = (float*)d_out;       // ND
  float* zpos = out + ND;            // ND
  float* zneg = zpos + ND;           // ND (used as S2 temp during Laplacian)

  const int tb = 256;
  const int gE = (E + tb - 1) / tb;
  const int gN = (n + tb - 1) / tb;
  const int gS = 2048;

  // CSR-path workspace requirement:
  // dis(n) + S1(ND) + rowptrL(n) + colL(E) + wL(E) + rowptrN(n) + colN(En) + wN(En)
  size_t need = sizeof(float) * ((size_t)3 * n + (size_t)ND
                                 + 2 * (size_t)E + 2 * (size_t)En);

  if (ws_size >= need) {
    // ---------------- CSR path ----------------
    float* dis   = (float*)d_ws;          // n
    float* S1    = dis + n;               // ND
    int*   rpL   = (int*)(S1 + ND);       // n
    int*   colL  = rpL + n;               // E
    float* wL    = (float*)(colL + E);    // E
    int*   rpN   = (int*)(wL + E);        // n
    int*   colN  = rpN + n;               // En
    float* wN    = (float*)(colN + En);   // En

    // degree + histograms
    hipMemsetAsync(dis, 0, (size_t)n * sizeof(float), stream);
    hipMemsetAsync(rpL, 0, (size_t)n * sizeof(int), stream);
    hipMemsetAsync(rpN, 0, (size_t)n * sizeof(int), stream);
    k_hist<true><<<gE, tb, 0, stream>>>(erow, ew, rpL, dis, E);
    k_hist<false><<<gE, tb, 0, stream>>>(nrow, nullptr, rpN, nullptr, En);
    k_dis<<<gN, tb, 0, stream>>>(dis, n);

    // scans (exclusive, in place)
    k_scan<<<1, 1024, 0, stream>>>(rpL, n);
    k_scan<<<1, 1024, 0, stream>>>(rpN, n);

    // permutes (rowptr becomes shifted ends)
    k_permute<true><<<gE, tb, 0, stream>>>(erow, ecol, ew, dis, rpL, colL, wL, E);
    k_permute<false><<<gE, tb, 0, stream>>>(nrow, ncol, nwt, nullptr, rpN, colN, wN, En);

    // Laplacian: S1 = Anorm@x ; S2(zneg) = Anorm@S1 ; out = combine
    k_spmm_csr<false><<<gS, tb, 0, stream>>>(rpL, colL, wL, x, S1, nullptr, n);
    k_spmm_csr<false><<<gS, tb, 0, stream>>>(rpL, colL, wL, S1, zneg, nullptr, n);
    k_combine<<<gS, tb, 0, stream>>>(x, S1, zneg, temp, out, ND / 4);

    // z_pos = Nmm(Nmm(out))
    k_spmm_csr<false><<<gS, tb, 0, stream>>>(rpN, colN, wN, out, S1, nullptr, n);
    k_spmm_csr<false><<<gS, tb, 0, stream>>>(rpN, colN, wN, S1, zpos, nullptr, n);

    // z_neg = Nmm(Nmm(out[shuf]))
    k_spmm_csr<true><<<gS, tb, 0, stream>>>(rpN, colN, wN, out, S1, shuf, n);
    k_spmm_csr<false><<<gS, tb, 0, stream>>>(rpN, colN, wN, S1, zneg, nullptr, n);
  } else {
    // ---------------- proven atomic fallback (round 3) ----------------
    float* dis = (float*)d_ws;
    float* S1  = dis + n;

    hipMemsetAsync(dis, 0, (size_t)n * sizeof(float), stream);
    k_deg<<<gE, tb, 0, stream>>>(erow, ew, dis, E);
    k_dis<<<gN, tb, 0, stream>>>(dis, n);

    hipMemsetAsync(S1, 0, (size_t)ND * sizeof(float), stream);
    k_spmm_atomic<false, true><<<gS, tb, 0, stream>>>(erow, ecol, ew, dis, x, S1, nullptr, E);
    hipMemsetAsync(zneg, 0, (size_t)ND * sizeof(float), stream);
    k_spmm_atomic<false, true><<<gS, tb, 0, stream>>>(erow, ecol, ew, dis, S1, zneg, nullptr, E);

    k_combine<<<gS, tb, 0, stream>>>(x, S1, zneg, temp, out, ND / 4);

    hipMemsetAsync(S1, 0, (size_t)ND * sizeof(float), stream);
    k_spmm_atomic<false, false><<<gS, tb, 0, stream>>>(nrow, ncol, nwt, nullptr, out, S1, nullptr, En);
    hipMemsetAsync(zpos, 0, (size_t)ND * sizeof(float), stream);
    k_spmm_atomic<false, false><<<gS, tb, 0, stream>>>(nrow, ncol, nwt, nullptr, S1, zpos, nullptr, En);

    hipMemsetAsync(S1, 0, (size_t)ND * sizeof(float), stream);
    k_spmm_atomic<true, false><<<gS, tb, 0, stream>>>(nrow, ncol, nwt, nullptr, out, S1, shuf, En);
    hipMemsetAsync(zneg, 0, (size_t)ND * sizeof(float), stream);
    k_spmm_atomic<false, false><<<gS, tb, 0, stream>>>(nrow, ncol, nwt, nullptr, S1, zneg, nullptr, En);
  }
}

// Round 6
// 1183.364 us; speedup vs baseline: 1.5118x; 1.2642x over previous
//
#include <hip/hip_runtime.h>

#define DIMF 64
#define SCAN_TPB 256
#define SCAN_VPT 8
#define SCAN_CHUNK (SCAN_TPB * SCAN_VPT)   // 2048 elements per block

// ============================ shared small kernels ============================

// deg -> dis in place: d>0 ? rsqrt(d) : 0
__global__ __launch_bounds__(256) void k_dis(float* __restrict__ deg, int n) {
  int i = blockIdx.x * 256 + threadIdx.x;
  if (i < n) {
    float d = deg[i];
    deg[i] = (d > 0.f) ? rsqrtf(d) : 0.f;
  }
}

// out = a*x + b*S1 + c2*S2   (float4-vectorized)
__global__ __launch_bounds__(256) void k_combine(const float* __restrict__ x,
    const float* __restrict__ s1, const float* __restrict__ s2,
    const float* __restrict__ temp, float* __restrict__ out, int n4) {
  float T0 = fmaxf(temp[0], 0.f);
  float T1 = fmaxf(temp[1], 0.f);
  float T2 = fmaxf(temp[2], 0.f);
  float c2 = (T0 + T2 - 2.f * T1) * 0.25f;
  float a = T1 + c2;                       // c0+c1+c2
  float b = -((T1 - T0) + 2.f * c2);       // -(c1+2c2)
  const float4* x4 = (const float4*)x;
  const float4* a4 = (const float4*)s1;
  const float4* b4 = (const float4*)s2;
  float4* o4 = (float4*)out;
  for (int i = blockIdx.x * 256 + threadIdx.x; i < n4; i += gridDim.x * 256) {
    float4 xv = x4[i], sv = a4[i], tv = b4[i];
    float4 r;
    r.x = a * xv.x + b * sv.x + c2 * tv.x;
    r.y = a * xv.y + b * sv.y + c2 * tv.y;
    r.z = a * xv.z + b * sv.z + c2 * tv.z;
    r.w = a * xv.w + b * sv.w + c2 * tv.w;
    o4[i] = r;
  }
}

// ============================ CSR build ============================

// counts[row[e]] += 1; optionally deg[row[e]] += w[e]
template <bool DEG>
__global__ __launch_bounds__(256) void k_hist(const int* __restrict__ row,
    const float* __restrict__ w, int* __restrict__ cnt,
    float* __restrict__ deg, int E) {
  for (int e = blockIdx.x * 256 + threadIdx.x; e < E; e += gridDim.x * 256) {
    int r = row[e];
    atomicAdd(&cnt[r], 1);
    if (DEG) atomicAdd(&deg[r], w[e]);
  }
}

// ---- hierarchical exclusive scan: phase 1 (block-local) ----
__global__ __launch_bounds__(SCAN_TPB) void k_scan1(int* __restrict__ a,
    int* __restrict__ partial, int n) {
  __shared__ int ts[SCAN_TPB];
  int base = blockIdx.x * SCAN_CHUNK + threadIdx.x * SCAN_VPT;
  int v[SCAN_VPT];
  int s = 0;
#pragma unroll
  for (int i = 0; i < SCAN_VPT; ++i) {
    int idx = base + i;
    v[i] = (idx < n) ? a[idx] : 0;
    s += v[i];
  }
  ts[threadIdx.x] = s;
  __syncthreads();
  for (int off = 1; off < SCAN_TPB; off <<= 1) {
    int t = (threadIdx.x >= off) ? ts[threadIdx.x - off] : 0;
    __syncthreads();
    ts[threadIdx.x] += t;
    __syncthreads();
  }
  int run = (threadIdx.x > 0) ? ts[threadIdx.x - 1] : 0;  // exclusive base
#pragma unroll
  for (int i = 0; i < SCAN_VPT; ++i) {
    int idx = base + i;
    if (idx < n) a[idx] = run;
    run += v[i];
  }
  if (threadIdx.x == SCAN_TPB - 1) partial[blockIdx.x] = ts[SCAN_TPB - 1];
}

// ---- phase 2: single-block exclusive scan of partials (nb <= 1024) ----
__global__ __launch_bounds__(1024) void k_scan2(int* __restrict__ partial, int nb) {
  __shared__ int ts[1024];
  int t = threadIdx.x;
  ts[t] = (t < nb) ? partial[t] : 0;
  __syncthreads();
  for (int off = 1; off < 1024; off <<= 1) {
    int v = (t >= off) ? ts[t - off] : 0;
    __syncthreads();
    ts[t] += v;
    __syncthreads();
  }
  if (t < nb) partial[t] = (t > 0) ? ts[t - 1] : 0;
}

// ---- phase 3: add block offsets ----
__global__ __launch_bounds__(SCAN_TPB) void k_scan3(int* __restrict__ a,
    const int* __restrict__ partial, int n) {
  int add = partial[blockIdx.x];
  int base = blockIdx.x * SCAN_CHUNK + threadIdx.x;
#pragma unroll
  for (int i = 0; i < SCAN_VPT; ++i) {
    int idx = base + i * SCAN_TPB;
    if (idx < n) a[idx] += add;
  }
}

// scatter edges into CSR order, packing (col, w) into int2.
// rowptr: exclusive starts on entry, SHIFTED ends on exit (rowptr[r] = end(r)).
template <bool NORM>
__global__ __launch_bounds__(256) void k_permute(const int* __restrict__ row,
    const int* __restrict__ col, const float* __restrict__ w,
    const float* __restrict__ dis, int* __restrict__ rowptr,
    int2* __restrict__ cw, int E) {
  for (int e = blockIdx.x * 256 + threadIdx.x; e < E; e += gridDim.x * 256) {
    int r = row[e];
    int c = col[e];
    float we = w[e];
    if (NORM) we *= dis[r] * dis[c];
    int p = atomicAdd(&rowptr[r], 1);
    cw[p] = make_int2(c, __float_as_int(we));
  }
}

// one wave per row, lane = feature. rend[r] = end(r), start = rend[r-1].
// dst fully written -> no memset, no atomics.
template <bool PERM>
__global__ __launch_bounds__(256) void k_spmm_csr(const int* __restrict__ rend,
    const int2* __restrict__ cw, const float* __restrict__ src,
    float* __restrict__ dst, const int* __restrict__ perm, int n) {
  int lane = threadIdx.x & 63;
  int wave = (blockIdx.x * 256 + threadIdx.x) >> 6;
  int nw = (gridDim.x * 256) >> 6;
  for (int r = wave; r < n; r += nw) {
    int s = (r > 0) ? rend[r - 1] : 0;
    int e = rend[r];
    float acc = 0.f;
    for (int j = s; j < e; ++j) {
      int2 q = cw[j];                      // wave-uniform 8B load
      int c = q.x;
      if (PERM) c = perm[c];
      acc += __int_as_float(q.y) * src[(size_t)c * DIMF + lane];
    }
    dst[(size_t)r * DIMF + lane] = acc;
  }
}

// ============================ atomic fallback path ============================

template <bool PERM, bool NORM>
__global__ __launch_bounds__(256) void k_spmm_atomic(const int* __restrict__ row,
    const int* __restrict__ col, const float* __restrict__ w,
    const float* __restrict__ dis, const float* __restrict__ src,
    float* __restrict__ dst, const int* __restrict__ perm, int E) {
  int lane = threadIdx.x & 63;
  int wave = (blockIdx.x * 256 + threadIdx.x) >> 6;
  int nwaves = (gridDim.x * 256) >> 6;
  for (int e = wave; e < E; e += nwaves) {
    int r = row[e];
    int c = col[e];
    float we = w[e];
    if (NORM) we *= dis[r] * dis[c];
    if (PERM) c = perm[c];
    float v = we * src[(size_t)c * DIMF + lane];
    atomicAdd(&dst[(size_t)r * DIMF + lane], v);
  }
}

__global__ __launch_bounds__(256) void k_deg(const int* __restrict__ row,
    const float* __restrict__ ew, float* __restrict__ deg, int E) {
  for (int e = blockIdx.x * 256 + threadIdx.x; e < E; e += gridDim.x * 256)
    atomicAdd(&deg[row[e]], ew[e]);
}

// ============================ launch ============================

extern "C" void kernel_launch(void* const* d_in, const int* in_sizes, int n_in,
                              void* d_out, int out_size, void* d_ws, size_t ws_size,
                              hipStream_t stream) {
  const float* x    = (const float*)d_in[0];
  const int*   shuf = (const int*)d_in[1];
  const int*   eidx = (const int*)d_in[2];
  const float* ew   = (const float*)d_in[3];
  const int*   nidx = (const int*)d_in[4];
  const float* nwt  = (const float*)d_in[5];
  const float* temp = (const float*)d_in[6];

  const int ND = in_sizes[0];        // N*64
  const int n  = ND / DIMF;          // N
  const int E  = in_sizes[2] / 2;    // edges (laplacian)
  const int En = in_sizes[4] / 2;    // edges (neighbor)

  const int* erow = eidx;
  const int* ecol = eidx + E;
  const int* nrow = nidx;
  const int* ncol = nidx + En;

  float* out  = (float*)d_out;       // ND
  float* zpos = out + ND;            // ND
  float* zneg = zpos + ND;           // ND (used as S2 temp during Laplacian)

  const int tb = 256;
  const int gE  = (E + tb - 1) / tb;
  const int gN  = (n + tb - 1) / tb;
  const int gS  = 2048;
  const int nbS = (n + SCAN_CHUNK - 1) / SCAN_CHUNK;   // scan blocks (<=1024)

  // ws: dis(n) + S1(ND) + rpL(n) + cwL(2E) + rpN(n) + cwN(2En) + partial(1024)
  size_t need = sizeof(float) * ((size_t)3 * n + (size_t)ND
                                 + 2 * (size_t)E + 2 * (size_t)En + 1024);

  if (ws_size >= need && nbS <= 1024) {
    // ---------------- CSR path ----------------
    float* dis   = (float*)d_ws;          // n
    float* S1    = dis + n;               // ND
    int*   rpL   = (int*)(S1 + ND);       // n
    int2*  cwL   = (int2*)(rpL + n);      // E
    int*   rpN   = (int*)(cwL + E);       // n
    int2*  cwN   = (int2*)(rpN + n);      // En
    int*   partial = (int*)(cwN + En);    // 1024

    // degree + histograms
    hipMemsetAsync(dis, 0, (size_t)n * sizeof(float), stream);
    hipMemsetAsync(rpL, 0, (size_t)n * sizeof(int), stream);
    hipMemsetAsync(rpN, 0, (size_t)n * sizeof(int), stream);
    k_hist<true><<<gE, tb, 0, stream>>>(erow, ew, rpL, dis, E);
    k_hist<false><<<gE, tb, 0, stream>>>(nrow, nullptr, rpN, nullptr, En);
    k_dis<<<gN, tb, 0, stream>>>(dis, n);

    // hierarchical exclusive scans
    k_scan1<<<nbS, SCAN_TPB, 0, stream>>>(rpL, partial, n);
    k_scan2<<<1, 1024, 0, stream>>>(partial, nbS);
    k_scan3<<<nbS, SCAN_TPB, 0, stream>>>(rpL, partial, n);
    k_scan1<<<nbS, SCAN_TPB, 0, stream>>>(rpN, partial, n);
    k_scan2<<<1, 1024, 0, stream>>>(partial, nbS);
    k_scan3<<<nbS, SCAN_TPB, 0, stream>>>(rpN, partial, n);

    // permutes (rowptr becomes shifted ends)
    k_permute<true><<<gE, tb, 0, stream>>>(erow, ecol, ew, dis, rpL, cwL, E);
    k_permute<false><<<gE, tb, 0, stream>>>(nrow, ncol, nwt, nullptr, rpN, cwN, En);

    // Laplacian: S1 = Anorm@x ; S2(zneg) = Anorm@S1 ; out = combine
    k_spmm_csr<false><<<gS, tb, 0, stream>>>(rpL, cwL, x, S1, nullptr, n);
    k_spmm_csr<false><<<gS, tb, 0, stream>>>(rpL, cwL, S1, zneg, nullptr, n);
    k_combine<<<gS, tb, 0, stream>>>(x, S1, zneg, temp, out, ND / 4);

    // z_pos = Nmm(Nmm(out))
    k_spmm_csr<false><<<gS, tb, 0, stream>>>(rpN, cwN, out, S1, nullptr, n);
    k_spmm_csr<false><<<gS, tb, 0, stream>>>(rpN, cwN, S1, zpos, nullptr, n);

    // z_neg = Nmm(Nmm(out[shuf]))
    k_spmm_csr<true><<<gS, tb, 0, stream>>>(rpN, cwN, out, S1, shuf, n);
    k_spmm_csr<false><<<gS, tb, 0, stream>>>(rpN, cwN, S1, zneg, nullptr, n);
  } else {
    // ---------------- proven atomic fallback (round 3) ----------------
    float* dis = (float*)d_ws;
    float* S1  = dis + n;

    hipMemsetAsync(dis, 0, (size_t)n * sizeof(float), stream);
    k_deg<<<gE, tb, 0, stream>>>(erow, ew, dis, E);
    k_dis<<<gN, tb, 0, stream>>>(dis, n);

    hipMemsetAsync(S1, 0, (size_t)ND * sizeof(float), stream);
    k_spmm_atomic<false, true><<<gS, tb, 0, stream>>>(erow, ecol, ew, dis, x, S1, nullptr, E);
    hipMemsetAsync(zneg, 0, (size_t)ND * sizeof(float), stream);
    k_spmm_atomic<false, true><<<gS, tb, 0, stream>>>(erow, ecol, ew, dis, S1, zneg, nullptr, E);

    k_combine<<<gS, tb, 0, stream>>>(x, S1, zneg, temp, out, ND / 4);

    hipMemsetAsync(S1, 0, (size_t)ND * sizeof(float), stream);
    k_spmm_atomic<false, false><<<gS, tb, 0, stream>>>(nrow, ncol, nwt, nullptr, out, S1, nullptr, En);
    hipMemsetAsync(zpos, 0, (size_t)ND * sizeof(float), stream);
    k_spmm_atomic<false, false><<<gS, tb, 0, stream>>>(nrow, ncol, nwt, nullptr, S1, zpos, nullptr, En);

    hipMemsetAsync(S1, 0, (size_t)ND * sizeof(float), stream);
    k_spmm_atomic<true, false><<<gS, tb, 0, stream>>>(nrow, ncol, nwt, nullptr, out, S1, shuf, En);
    hipMemsetAsync(zneg, 0, (size_t)ND * sizeof(float), stream);
    k_spmm_atomic<false, false><<<gS, tb, 0, stream>>>(nrow, ncol, nwt, nullptr, S1, zneg, nullptr, En);
  }
}

// Round 7
// 822.033 us; speedup vs baseline: 2.1763x; 1.4396x over previous
//
#include <hip/hip_runtime.h>

#define DIMF 64
#define SCAN_TPB 256
#define SCAN_VPT 8
#define SCAN_CHUNK (SCAN_TPB * SCAN_VPT)   // 2048 elements per block

// ============================ shared small kernels ============================

// deg -> dis in place: d>0 ? rsqrt(d) : 0
__global__ __launch_bounds__(256) void k_dis(float* __restrict__ deg, int n) {
  int i = blockIdx.x * 256 + threadIdx.x;
  if (i < n) {
    float d = deg[i];
    deg[i] = (d > 0.f) ? rsqrtf(d) : 0.f;
  }
}

// out = a*x + b*S1 + c2*S2   (float4-vectorized)
__global__ __launch_bounds__(256) void k_combine(const float* __restrict__ x,
    const float* __restrict__ s1, const float* __restrict__ s2,
    const float* __restrict__ temp, float* __restrict__ out, int n4) {
  float T0 = fmaxf(temp[0], 0.f);
  float T1 = fmaxf(temp[1], 0.f);
  float T2 = fmaxf(temp[2], 0.f);
  float c2 = (T0 + T2 - 2.f * T1) * 0.25f;
  float a = T1 + c2;                       // c0+c1+c2
  float b = -((T1 - T0) + 2.f * c2);       // -(c1+2c2)
  const float4* x4 = (const float4*)x;
  const float4* a4 = (const float4*)s1;
  const float4* b4 = (const float4*)s2;
  float4* o4 = (float4*)out;
  for (int i = blockIdx.x * 256 + threadIdx.x; i < n4; i += gridDim.x * 256) {
    float4 xv = x4[i], sv = a4[i], tv = b4[i];
    float4 r;
    r.x = a * xv.x + b * sv.x + c2 * tv.x;
    r.y = a * xv.y + b * sv.y + c2 * tv.y;
    r.z = a * xv.z + b * sv.z + c2 * tv.z;
    r.w = a * xv.w + b * sv.w + c2 * tv.w;
    o4[i] = r;
  }
}

// ============================ CSR build ============================

// counts[row[e]] += 1; optionally deg[row[e]] += w[e]
template <bool DEG>
__global__ __launch_bounds__(256) void k_hist(const int* __restrict__ row,
    const float* __restrict__ w, int* __restrict__ cnt,
    float* __restrict__ deg, int E) {
  for (int e = blockIdx.x * 256 + threadIdx.x; e < E; e += gridDim.x * 256) {
    int r = row[e];
    atomicAdd(&cnt[r], 1);
    if (DEG) atomicAdd(&deg[r], w[e]);
  }
}

// ---- hierarchical exclusive scan: phase 1 (block-local) ----
__global__ __launch_bounds__(SCAN_TPB) void k_scan1(int* __restrict__ a,
    int* __restrict__ partial, int n) {
  __shared__ int ts[SCAN_TPB];
  int base = blockIdx.x * SCAN_CHUNK + threadIdx.x * SCAN_VPT;
  int v[SCAN_VPT];
  int s = 0;
#pragma unroll
  for (int i = 0; i < SCAN_VPT; ++i) {
    int idx = base + i;
    v[i] = (idx < n) ? a[idx] : 0;
    s += v[i];
  }
  ts[threadIdx.x] = s;
  __syncthreads();
  for (int off = 1; off < SCAN_TPB; off <<= 1) {
    int t = (threadIdx.x >= off) ? ts[threadIdx.x - off] : 0;
    __syncthreads();
    ts[threadIdx.x] += t;
    __syncthreads();
  }
  int run = (threadIdx.x > 0) ? ts[threadIdx.x - 1] : 0;  // exclusive base
#pragma unroll
  for (int i = 0; i < SCAN_VPT; ++i) {
    int idx = base + i;
    if (idx < n) a[idx] = run;
    run += v[i];
  }
  if (threadIdx.x == SCAN_TPB - 1) partial[blockIdx.x] = ts[SCAN_TPB - 1];
}

// ---- phase 2: single-block exclusive scan of partials (nb <= 1024) ----
__global__ __launch_bounds__(1024) void k_scan2(int* __restrict__ partial, int nb) {
  __shared__ int ts[1024];
  int t = threadIdx.x;
  ts[t] = (t < nb) ? partial[t] : 0;
  __syncthreads();
  for (int off = 1; off < 1024; off <<= 1) {
    int v = (t >= off) ? ts[t - off] : 0;
    __syncthreads();
    ts[t] += v;
    __syncthreads();
  }
  if (t < nb) partial[t] = (t > 0) ? ts[t - 1] : 0;
}

// ---- phase 3: add block offsets ----
__global__ __launch_bounds__(SCAN_TPB) void k_scan3(int* __restrict__ a,
    const int* __restrict__ partial, int n) {
  int add = partial[blockIdx.x];
  int base = blockIdx.x * SCAN_CHUNK + threadIdx.x;
#pragma unroll
  for (int i = 0; i < SCAN_VPT; ++i) {
    int idx = base + i * SCAN_TPB;
    if (idx < n) a[idx] += add;
  }
}

// scatter edges into CSR order, packing (col, w) into int2.
// rowptr: exclusive starts on entry, SHIFTED ends on exit (rowptr[r] = end(r)).
template <bool NORM>
__global__ __launch_bounds__(256) void k_permute(const int* __restrict__ row,
    const int* __restrict__ col, const float* __restrict__ w,
    const float* __restrict__ dis, int* __restrict__ rowptr,
    int2* __restrict__ cw, int E) {
  for (int e = blockIdx.x * 256 + threadIdx.x; e < E; e += gridDim.x * 256) {
    int r = row[e];
    int c = col[e];
    float we = w[e];
    if (NORM) we *= dis[r] * dis[c];
    int p = atomicAdd(&rowptr[r], 1);
    cw[p] = make_int2(c, __float_as_int(we));
  }
}

// one wave per row, lane = feature. rend[r] = end(r), start = rend[r-1].
// 4-way edge unroll: 4 independent (cw load -> gather) chains in flight
// per wave -> 4x memory-level parallelism on the latency-bound gather.
template <bool PERM>
__global__ __launch_bounds__(256) void k_spmm_csr(const int* __restrict__ rend,
    const int2* __restrict__ cw, const float* __restrict__ src,
    float* __restrict__ dst, const int* __restrict__ perm, int n) {
  int lane = threadIdx.x & 63;
  int wave = (blockIdx.x * 256 + threadIdx.x) >> 6;
  int nw = (gridDim.x * 256) >> 6;
  for (int r = wave; r < n; r += nw) {
    int s = (r > 0) ? rend[r - 1] : 0;
    int e = rend[r];
    float acc = 0.f;
    int j = s;
    for (; j + 3 < e; j += 4) {
      int2 q0 = cw[j];
      int2 q1 = cw[j + 1];
      int2 q2 = cw[j + 2];
      int2 q3 = cw[j + 3];
      int c0 = q0.x, c1 = q1.x, c2 = q2.x, c3 = q3.x;
      if (PERM) {
        c0 = perm[c0]; c1 = perm[c1]; c2 = perm[c2]; c3 = perm[c3];
      }
      float v0 = src[(size_t)c0 * DIMF + lane];
      float v1 = src[(size_t)c1 * DIMF + lane];
      float v2 = src[(size_t)c2 * DIMF + lane];
      float v3 = src[(size_t)c3 * DIMF + lane];
      acc += __int_as_float(q0.y) * v0;
      acc += __int_as_float(q1.y) * v1;
      acc += __int_as_float(q2.y) * v2;
      acc += __int_as_float(q3.y) * v3;
    }
    for (; j < e; ++j) {
      int2 q = cw[j];
      int c = q.x;
      if (PERM) c = perm[c];
      acc += __int_as_float(q.y) * src[(size_t)c * DIMF + lane];
    }
    dst[(size_t)r * DIMF + lane] = acc;
  }
}

// ============================ atomic fallback path ============================

template <bool PERM, bool NORM>
__global__ __launch_bounds__(256) void k_spmm_atomic(const int* __restrict__ row,
    const int* __restrict__ col, const float* __restrict__ w,
    const float* __restrict__ dis, const float* __restrict__ src,
    float* __restrict__ dst, const int* __restrict__ perm, int E) {
  int lane = threadIdx.x & 63;
  int wave = (blockIdx.x * 256 + threadIdx.x) >> 6;
  int nwaves = (gridDim.x * 256) >> 6;
  for (int e = wave; e < E; e += nwaves) {
    int r = row[e];
    int c = col[e];
    float we = w[e];
    if (NORM) we *= dis[r] * dis[c];
    if (PERM) c = perm[c];
    float v = we * src[(size_t)c * DIMF + lane];
    atomicAdd(&dst[(size_t)r * DIMF + lane], v);
  }
}

__global__ __launch_bounds__(256) void k_deg(const int* __restrict__ row,
    const float* __restrict__ ew, float* __restrict__ deg, int E) {
  for (int e = blockIdx.x * 256 + threadIdx.x; e < E; e += gridDim.x * 256)
    atomicAdd(&deg[row[e]], ew[e]);
}

// ============================ launch ============================

extern "C" void kernel_launch(void* const* d_in, const int* in_sizes, int n_in,
                              void* d_out, int out_size, void* d_ws, size_t ws_size,
                              hipStream_t stream) {
  const float* x    = (const float*)d_in[0];
  const int*   shuf = (const int*)d_in[1];
  const int*   eidx = (const int*)d_in[2];
  const float* ew   = (const float*)d_in[3];
  const int*   nidx = (const int*)d_in[4];
  const float* nwt  = (const float*)d_in[5];
  const float* temp = (const float*)d_in[6];

  const int ND = in_sizes[0];        // N*64
  const int n  = ND / DIMF;          // N
  const int E  = in_sizes[2] / 2;    // edges (laplacian)
  const int En = in_sizes[4] / 2;    // edges (neighbor)

  const int* erow = eidx;
  const int* ecol = eidx + E;
  const int* nrow = nidx;
  const int* ncol = nidx + En;

  float* out  = (float*)d_out;       // ND
  float* zpos = out + ND;            // ND
  float* zneg = zpos + ND;           // ND (used as S2 temp during Laplacian)

  const int tb = 256;
  const int gE  = (E + tb - 1) / tb;
  const int gN  = (n + tb - 1) / tb;
  const int gS  = 2048;
  const int nbS = (n + SCAN_CHUNK - 1) / SCAN_CHUNK;   // scan blocks (<=1024)

  // ws: dis(n) + S1(ND) + rpL(n) + cwL(2E) + rpN(n) + cwN(2En) + partial(1024)
  size_t need = sizeof(float) * ((size_t)3 * n + (size_t)ND
                                 + 2 * (size_t)E + 2 * (size_t)En + 1024);

  if (ws_size >= need && nbS <= 1024) {
    // ---------------- CSR path ----------------
    float* dis   = (float*)d_ws;          // n
    float* S1    = dis + n;               // ND
    int*   rpL   = (int*)(S1 + ND);       // n
    int2*  cwL   = (int2*)(rpL + n);      // E
    int*   rpN   = (int*)(cwL + E);       // n
    int2*  cwN   = (int2*)(rpN + n);      // En
    int*   partial = (int*)(cwN + En);    // 1024

    // degree + histograms
    hipMemsetAsync(dis, 0, (size_t)n * sizeof(float), stream);
    hipMemsetAsync(rpL, 0, (size_t)n * sizeof(int), stream);
    hipMemsetAsync(rpN, 0, (size_t)n * sizeof(int), stream);
    k_hist<true><<<gE, tb, 0, stream>>>(erow, ew, rpL, dis, E);
    k_hist<false><<<gE, tb, 0, stream>>>(nrow, nullptr, rpN, nullptr, En);
    k_dis<<<gN, tb, 0, stream>>>(dis, n);

    // hierarchical exclusive scans
    k_scan1<<<nbS, SCAN_TPB, 0, stream>>>(rpL, partial, n);
    k_scan2<<<1, 1024, 0, stream>>>(partial, nbS);
    k_scan3<<<nbS, SCAN_TPB, 0, stream>>>(rpL, partial, n);
    k_scan1<<<nbS, SCAN_TPB, 0, stream>>>(rpN, partial, n);
    k_scan2<<<1, 1024, 0, stream>>>(partial, nbS);
    k_scan3<<<nbS, SCAN_TPB, 0, stream>>>(rpN, partial, n);

    // permutes (rowptr becomes shifted ends)
    k_permute<true><<<gE, tb, 0, stream>>>(erow, ecol, ew, dis, rpL, cwL, E);
    k_permute<false><<<gE, tb, 0, stream>>>(nrow, ncol, nwt, nullptr, rpN, cwN, En);

    // Laplacian: S1 = Anorm@x ; S2(zneg) = Anorm@S1 ; out = combine
    k_spmm_csr<false><<<gS, tb, 0, stream>>>(rpL, cwL, x, S1, nullptr, n);
    k_spmm_csr<false><<<gS, tb, 0, stream>>>(rpL, cwL, S1, zneg, nullptr, n);
    k_combine<<<gS, tb, 0, stream>>>(x, S1, zneg, temp, out, ND / 4);

    // z_pos = Nmm(Nmm(out))
    k_spmm_csr<false><<<gS, tb, 0, stream>>>(rpN, cwN, out, S1, nullptr, n);
    k_spmm_csr<false><<<gS, tb, 0, stream>>>(rpN, cwN, S1, zpos, nullptr, n);

    // z_neg = Nmm(Nmm(out[shuf]))
    k_spmm_csr<true><<<gS, tb, 0, stream>>>(rpN, cwN, out, S1, shuf, n);
    k_spmm_csr<false><<<gS, tb, 0, stream>>>(rpN, cwN, S1, zneg, nullptr, n);
  } else {
    // ---------------- proven atomic fallback (round 3) ----------------
    float* dis = (float*)d_ws;
    float* S1  = dis + n;

    hipMemsetAsync(dis, 0, (size_t)n * sizeof(float), stream);
    k_deg<<<gE, tb, 0, stream>>>(erow, ew, dis, E);
    k_dis<<<gN, tb, 0, stream>>>(dis, n);

    hipMemsetAsync(S1, 0, (size_t)ND * sizeof(float), stream);
    k_spmm_atomic<false, true><<<gS, tb, 0, stream>>>(erow, ecol, ew, dis, x, S1, nullptr, E);
    hipMemsetAsync(zneg, 0, (size_t)ND * sizeof(float), stream);
    k_spmm_atomic<false, true><<<gS, tb, 0, stream>>>(erow, ecol, ew, dis, S1, zneg, nullptr, E);

    k_combine<<<gS, tb, 0, stream>>>(x, S1, zneg, temp, out, ND / 4);

    hipMemsetAsync(S1, 0, (size_t)ND * sizeof(float), stream);
    k_spmm_atomic<false, false><<<gS, tb, 0, stream>>>(nrow, ncol, nwt, nullptr, out, S1, nullptr, En);
    hipMemsetAsync(zpos, 0, (size_t)ND * sizeof(float), stream);
    k_spmm_atomic<false, false><<<gS, tb, 0, stream>>>(nrow, ncol, nwt, nullptr, S1, zpos, nullptr, En);

    hipMemsetAsync(S1, 0, (size_t)ND * sizeof(float), stream);
    k_spmm_atomic<true, false><<<gS, tb, 0, stream>>>(nrow, ncol, nwt, nullptr, out, S1, shuf, En);
    hipMemsetAsync(zneg, 0, (size_t)ND * sizeof(float), stream);
    k_spmm_atomic<false, false><<<gS, tb, 0, stream>>>(nrow, ncol, nwt, nullptr, S1, zneg, nullptr, En);
  }
}

// Round 9
// 745.062 us; speedup vs baseline: 2.4011x; 1.1033x over previous
//
#include <hip/hip_runtime.h>

#define DIMF 64
#define SCAN_TPB 256
#define SCAN_VPT 8
#define SCAN_CHUNK (SCAN_TPB * SCAN_VPT)   // 2048 elements per block

typedef unsigned long long u64;
typedef unsigned int u32;

// ============================ CSR build ============================

// L-graph histogram: ONE 64-bit atomic per edge packs {cnt:hi32, deg:lo32 fixed-point 2^-24}.
// Max per-row weight sum ~45 -> fx sum < 2^31, never carries into cnt.
__global__ __launch_bounds__(256) void k_hist_pack(const int* __restrict__ row,
    const float* __restrict__ w, u64* __restrict__ pairs, int E) {
  for (int e = blockIdx.x * 256 + threadIdx.x; e < E; e += gridDim.x * 256) {
    u32 fx = (u32)__float2uint_rn(w[e] * 16777216.0f);   // w * 2^24
    atomicAdd(&pairs[row[e]], (1ULL << 32) | (u64)fx);
  }
}

// N-graph histogram: count only
__global__ __launch_bounds__(256) void k_hist_cnt(const int* __restrict__ row,
    int* __restrict__ cnt, int E) {
  for (int e = blockIdx.x * 256 + threadIdx.x; e < E; e += gridDim.x * 256)
    atomicAdd(&cnt[row[e]], 1);
}

// unpack pairs -> rpL (counts) and dis = deg>0 ? rsqrt(deg) : 0
__global__ __launch_bounds__(256) void k_unpack(const u64* __restrict__ pairs,
    int* __restrict__ rpL, float* __restrict__ dis, int n) {
  int i = blockIdx.x * 256 + threadIdx.x;
  if (i < n) {
    u64 p = pairs[i];
    rpL[i] = (int)(p >> 32);
    float d = (float)(u32)p * 5.9604644775390625e-8f;    // 2^-24
    dis[i] = (d > 0.f) ? rsqrtf(d) : 0.f;
  }
}

// ---- hierarchical exclusive scan ----
__global__ __launch_bounds__(SCAN_TPB) void k_scan1(int* __restrict__ a,
    int* __restrict__ partial, int n) {
  __shared__ int ts[SCAN_TPB];
  int base = blockIdx.x * SCAN_CHUNK + threadIdx.x * SCAN_VPT;
  int v[SCAN_VPT];
  int s = 0;
#pragma unroll
  for (int i = 0; i < SCAN_VPT; ++i) {
    int idx = base + i;
    v[i] = (idx < n) ? a[idx] : 0;
    s += v[i];
  }
  ts[threadIdx.x] = s;
  __syncthreads();
  for (int off = 1; off < SCAN_TPB; off <<= 1) {
    int t = (threadIdx.x >= off) ? ts[threadIdx.x - off] : 0;
    __syncthreads();
    ts[threadIdx.x] += t;
    __syncthreads();
  }
  int run = (threadIdx.x > 0) ? ts[threadIdx.x - 1] : 0;
#pragma unroll
  for (int i = 0; i < SCAN_VPT; ++i) {
    int idx = base + i;
    if (idx < n) a[idx] = run;
    run += v[i];
  }
  if (threadIdx.x == SCAN_TPB - 1) partial[blockIdx.x] = ts[SCAN_TPB - 1];
}

__global__ __launch_bounds__(1024) void k_scan2(int* __restrict__ partial, int nb) {
  __shared__ int ts[1024];
  int t = threadIdx.x;
  ts[t] = (t < nb) ? partial[t] : 0;
  __syncthreads();
  for (int off = 1; off < 1024; off <<= 1) {
    int v = (t >= off) ? ts[t - off] : 0;
    __syncthreads();
    ts[t] += v;
    __syncthreads();
  }
  if (t < nb) partial[t] = (t > 0) ? ts[t - 1] : 0;
}

__global__ __launch_bounds__(SCAN_TPB) void k_scan3(int* __restrict__ a,
    const int* __restrict__ partial, int n) {
  int add = partial[blockIdx.x];
  int base = blockIdx.x * SCAN_CHUNK + threadIdx.x;
#pragma unroll
  for (int i = 0; i < SCAN_VPT; ++i) {
    int idx = base + i * SCAN_TPB;
    if (idx < n) a[idx] += add;
  }
}

// scatter edges into CSR order, packing (col, w) into int2.
// rowptr: exclusive starts on entry, SHIFTED ends on exit (rowptr[r] = end(r)).
template <bool NORM>
__global__ __launch_bounds__(256) void k_permute(const int* __restrict__ row,
    const int* __restrict__ col, const float* __restrict__ w,
    const float* __restrict__ dis, int* __restrict__ rowptr,
    int2* __restrict__ cw, int E) {
  for (int e = blockIdx.x * 256 + threadIdx.x; e < E; e += gridDim.x * 256) {
    int r = row[e];
    int c = col[e];
    float we = w[e];
    if (NORM) we *= dis[r] * dis[c];
    int p = atomicAdd(&rowptr[r], 1);
    cw[p] = make_int2(c, __float_as_int(we));
  }
}

// ============================ SpMM kernels ============================

// one wave per row, lane = feature; 8-way edge unroll for MLP.
template <bool PERM>
__global__ __launch_bounds__(256) void k_spmm_csr(const int* __restrict__ rend,
    const int2* __restrict__ cw, const float* __restrict__ src,
    float* __restrict__ dst, const int* __restrict__ perm, int n) {
  int lane = threadIdx.x & 63;
  int wave = (blockIdx.x * 256 + threadIdx.x) >> 6;
  int nw = (gridDim.x * 256) >> 6;
  for (int r = wave; r < n; r += nw) {
    int s = (r > 0) ? rend[r - 1] : 0;
    int e = rend[r];
    float acc = 0.f;
    int j = s;
    for (; j + 7 < e; j += 8) {
      int2 q[8];
      float v[8];
#pragma unroll
      for (int k = 0; k < 8; ++k) q[k] = cw[j + k];
#pragma unroll
      for (int k = 0; k < 8; ++k) {
        int c = q[k].x;
        if (PERM) c = perm[c];
        v[k] = src[(size_t)c * DIMF + lane];
      }
#pragma unroll
      for (int k = 0; k < 8; ++k) acc += __int_as_float(q[k].y) * v[k];
    }
    for (; j < e; ++j) {
      int2 q = cw[j];
      int c = q.x;
      if (PERM) c = perm[c];
      acc += __int_as_float(q.y) * src[(size_t)c * DIMF + lane];
    }
    dst[(size_t)r * DIMF + lane] = acc;
  }
}

// L-level-2 SpMM fused with combine: out = a*x + b*s1 + c2*(A @ s1)
__global__ __launch_bounds__(256) void k_spmm_combine(const int* __restrict__ rend,
    const int2* __restrict__ cw, const float* __restrict__ s1,
    const float* __restrict__ x, const float* __restrict__ temp,
    float* __restrict__ out, int n) {
  float T0 = fmaxf(temp[0], 0.f);
  float T1 = fmaxf(temp[1], 0.f);
  float T2 = fmaxf(temp[2], 0.f);
  float c2 = (T0 + T2 - 2.f * T1) * 0.25f;
  float a = T1 + c2;
  float b = -((T1 - T0) + 2.f * c2);
  int lane = threadIdx.x & 63;
  int wave = (blockIdx.x * 256 + threadIdx.x) >> 6;
  int nw = (gridDim.x * 256) >> 6;
  for (int r = wave; r < n; r += nw) {
    int s = (r > 0) ? rend[r - 1] : 0;
    int e = rend[r];
    float acc = 0.f;
    int j = s;
    for (; j + 7 < e; j += 8) {
      int2 q[8];
      float v[8];
#pragma unroll
      for (int k = 0; k < 8; ++k) q[k] = cw[j + k];
#pragma unroll
      for (int k = 0; k < 8; ++k) v[k] = s1[(size_t)q[k].x * DIMF + lane];
#pragma unroll
      for (int k = 0; k < 8; ++k) acc += __int_as_float(q[k].y) * v[k];
    }
    for (; j < e; ++j) {
      int2 q = cw[j];
      acc += __int_as_float(q.y) * s1[(size_t)q.x * DIMF + lane];
    }
    size_t o = (size_t)r * DIMF + lane;
    out[o] = a * x[o] + b * s1[o] + c2 * acc;
  }
}

// dual-input SpMM: dst0[r] = sum w*src[c], dst1[r] = sum w*src[perm[c]]
// shares rowptr/cw stream; 4-way edge unroll x 2 gathers = 8 loads in flight.
__global__ __launch_bounds__(256) void k_spmm_dual(const int* __restrict__ rend,
    const int2* __restrict__ cw, const float* __restrict__ src,
    float* __restrict__ dst0, float* __restrict__ dst1,
    const int* __restrict__ perm, int n) {
  int lane = threadIdx.x & 63;
  int wave = (blockIdx.x * 256 + threadIdx.x) >> 6;
  int nw = (gridDim.x * 256) >> 6;
  for (int r = wave; r < n; r += nw) {
    int s = (r > 0) ? rend[r - 1] : 0;
    int e = rend[r];
    float acc0 = 0.f, acc1 = 0.f;
    int j = s;
    for (; j + 3 < e; j += 4) {
      int2 q[4];
      float v0[4], v1[4];
#pragma unroll
      for (int k = 0; k < 4; ++k) q[k] = cw[j + k];
#pragma unroll
      for (int k = 0; k < 4; ++k) {
        int c = q[k].x;
        int cp = perm[c];
        v0[k] = src[(size_t)c * DIMF + lane];
        v1[k] = src[(size_t)cp * DIMF + lane];
      }
#pragma unroll
      for (int k = 0; k < 4; ++k) {
        float wv = __int_as_float(q[k].y);
        acc0 += wv * v0[k];
        acc1 += wv * v1[k];
      }
    }
    for (; j < e; ++j) {
      int2 q = cw[j];
      float wv = __int_as_float(q.y);
      acc0 += wv * src[(size_t)q.x * DIMF + lane];
      acc1 += wv * src[(size_t)perm[q.x] * DIMF + lane];
    }
    dst0[(size_t)r * DIMF + lane] = acc0;
    dst1[(size_t)r * DIMF + lane] = acc1;
  }
}

// ============================ atomic fallback path ============================

__global__ __launch_bounds__(256) void k_dis_fb(float* __restrict__ deg, int n) {
  int i = blockIdx.x * 256 + threadIdx.x;
  if (i < n) {
    float d = deg[i];
    deg[i] = (d > 0.f) ? rsqrtf(d) : 0.f;
  }
}

__global__ __launch_bounds__(256) void k_combine_fb(const float* __restrict__ x,
    const float* __restrict__ s1, const float* __restrict__ s2,
    const float* __restrict__ temp, float* __restrict__ out, int n4) {
  float T0 = fmaxf(temp[0], 0.f);
  float T1 = fmaxf(temp[1], 0.f);
  float T2 = fmaxf(temp[2], 0.f);
  float c2 = (T0 + T2 - 2.f * T1) * 0.25f;
  float a = T1 + c2;
  float b = -((T1 - T0) + 2.f * c2);
  const float4* x4 = (const float4*)x;
  const float4* a4 = (const float4*)s1;
  const float4* b4 = (const float4*)s2;
  float4* o4 = (float4*)out;
  for (int i = blockIdx.x * 256 + threadIdx.x; i < n4; i += gridDim.x * 256) {
    float4 xv = x4[i], sv = a4[i], tv = b4[i];
    float4 r;
    r.x = a * xv.x + b * sv.x + c2 * tv.x;
    r.y = a * xv.y + b * sv.y + c2 * tv.y;
    r.z = a * xv.z + b * sv.z + c2 * tv.z;
    r.w = a * xv.w + b * sv.w + c2 * tv.w;
    o4[i] = r;
  }
}

template <bool PERM, bool NORM>
__global__ __launch_bounds__(256) void k_spmm_atomic(const int* __restrict__ row,
    const int* __restrict__ col, const float* __restrict__ w,
    const float* __restrict__ dis, const float* __restrict__ src,
    float* __restrict__ dst, const int* __restrict__ perm, int E) {
  int lane = threadIdx.x & 63;
  int wave = (blockIdx.x * 256 + threadIdx.x) >> 6;
  int nwaves = (gridDim.x * 256) >> 6;
  for (int e = wave; e < E; e += nwaves) {
    int r = row[e];
    int c = col[e];
    float we = w[e];
    if (NORM) we *= dis[r] * dis[c];
    if (PERM) c = perm[c];
    float v = we * src[(size_t)c * DIMF + lane];
    atomicAdd(&dst[(size_t)r * DIMF + lane], v);
  }
}

__global__ __launch_bounds__(256) void k_deg_fb(const int* __restrict__ row,
    const float* __restrict__ ew, float* __restrict__ deg, int E) {
  for (int e = blockIdx.x * 256 + threadIdx.x; e < E; e += gridDim.x * 256)
    atomicAdd(&deg[row[e]], ew[e]);
}

// ============================ launch ============================

extern "C" void kernel_launch(void* const* d_in, const int* in_sizes, int n_in,
                              void* d_out, int out_size, void* d_ws, size_t ws_size,
                              hipStream_t stream) {
  const float* x    = (const float*)d_in[0];
  const int*   shuf = (const int*)d_in[1];
  const int*   eidx = (const int*)d_in[2];
  const float* ew   = (const float*)d_in[3];
  const int*   nidx = (const int*)d_in[4];
  const float* nwt  = (const float*)d_in[5];
  const float* temp = (const float*)d_in[6];

  const int ND = in_sizes[0];
  const int n  = ND / DIMF;
  const int E  = in_sizes[2] / 2;
  const int En = in_sizes[4] / 2;

  const int* erow = eidx;
  const int* ecol = eidx + E;
  const int* nrow = nidx;
  const int* ncol = nidx + En;

  float* out  = (float*)d_out;       // ND
  float* zpos = out + ND;            // ND (also neg-mid temp)
  float* zneg = zpos + ND;           // ND (also S2 temp in Laplacian for fallback)

  const int tb = 256;
  const int gE  = (E + tb - 1) / tb;
  const int gN  = (n + tb - 1) / tb;
  const int gS  = 2048;
  const int nbS = (n + SCAN_CHUNK - 1) / SCAN_CHUNK;

  // ws: dis(n) + S1(ND) + rpL(n) + cwL(2E) + rpN(n) + cwN(2En) + partial(1024)
  // pairs (u64 x n) OVERLAYS cwL (free until permute) -> no extra space.
  size_t need = sizeof(float) * ((size_t)3 * n + (size_t)ND
                                 + 2 * (size_t)E + 2 * (size_t)En + 1024);

  if (ws_size >= need && nbS <= 1024 && 2 * (size_t)E >= 2 * (size_t)n) {
    // ---------------- CSR path ----------------
    float* dis   = (float*)d_ws;          // n
    float* S1    = dis + n;               // ND
    int*   rpL   = (int*)(S1 + ND);       // n
    int2*  cwL   = (int2*)(rpL + n);      // E
    int*   rpN   = (int*)(cwL + E);       // n
    int2*  cwN   = (int2*)(rpN + n);      // En
    int*   partial = (int*)(cwN + En);    // 1024
    u64*   pairs = (u64*)cwL;             // n u64, overlay (dead before permute)

    // histograms
    hipMemsetAsync(pairs, 0, (size_t)n * sizeof(u64), stream);
    hipMemsetAsync(rpN, 0, (size_t)n * sizeof(int), stream);
    k_hist_pack<<<gE, tb, 0, stream>>>(erow, ew, pairs, E);
    k_hist_cnt<<<gE, tb, 0, stream>>>(nrow, rpN, En);
    k_unpack<<<gN, tb, 0, stream>>>(pairs, rpL, dis, n);

    // exclusive scans
    k_scan1<<<nbS, SCAN_TPB, 0, stream>>>(rpL, partial, n);
    k_scan2<<<1, 1024, 0, stream>>>(partial, nbS);
    k_scan3<<<nbS, SCAN_TPB, 0, stream>>>(rpL, partial, n);
    k_scan1<<<nbS, SCAN_TPB, 0, stream>>>(rpN, partial, n);
    k_scan2<<<1, 1024, 0, stream>>>(partial, nbS);
    k_scan3<<<nbS, SCAN_TPB, 0, stream>>>(rpN, partial, n);

    // CSR scatter (overwrites pairs region with cwL -- pairs already consumed)
    k_permute<true><<<gE, tb, 0, stream>>>(erow, ecol, ew, dis, rpL, cwL, E);
    k_permute<false><<<gE, tb, 0, stream>>>(nrow, ncol, nwt, nullptr, rpN, cwN, En);

    // Laplacian: S1 = Anorm@x ; out = a*x + b*S1 + c2*(Anorm@S1)  [fused]
    k_spmm_csr<false><<<gS, tb, 0, stream>>>(rpL, cwL, x, S1, nullptr, n);
    k_spmm_combine<<<gS, tb, 0, stream>>>(rpL, cwL, S1, x, temp, out, n);

    // level-1 dual: S1 = Nmm(out) [pos-mid], zpos = Nmm(out[shuf]) [neg-mid]
    k_spmm_dual<<<gS, tb, 0, stream>>>(rpN, cwN, out, S1, zpos, shuf, n);
    // level-2: zneg = Nmm(neg-mid) first (frees zpos), then zpos = Nmm(pos-mid)
    k_spmm_csr<false><<<gS, tb, 0, stream>>>(rpN, cwN, zpos, zneg, nullptr, n);
    k_spmm_csr<false><<<gS, tb, 0, stream>>>(rpN, cwN, S1, zpos, nullptr, n);
  } else {
    // ---------------- proven atomic fallback ----------------
    float* dis = (float*)d_ws;
    float* S1  = dis + n;

    hipMemsetAsync(dis, 0, (size_t)n * sizeof(float), stream);
    k_deg_fb<<<gE, tb, 0, stream>>>(erow, ew, dis, E);
    k_dis_fb<<<gN, tb, 0, stream>>>(dis, n);

    hipMemsetAsync(S1, 0, (size_t)ND * sizeof(float), stream);
    k_spmm_atomic<false, true><<<gS, tb, 0, stream>>>(erow, ecol, ew, dis, x, S1, nullptr, E);
    hipMemsetAsync(zneg, 0, (size_t)ND * sizeof(float), stream);
    k_spmm_atomic<false, true><<<gS, tb, 0, stream>>>(erow, ecol, ew, dis, S1, zneg, nullptr, E);

    k_combine_fb<<<gS, tb, 0, stream>>>(x, S1, zneg, temp, out, ND / 4);

    hipMemsetAsync(S1, 0, (size_t)ND * sizeof(float), stream);
    k_spmm_atomic<false, false><<<gS, tb, 0, stream>>>(nrow, ncol, nwt, nullptr, out, S1, nullptr, En);
    hipMemsetAsync(zpos, 0, (size_t)ND * sizeof(float), stream);
    k_spmm_atomic<false, false><<<gS, tb, 0, stream>>>(nrow, ncol, nwt, nullptr, S1, zpos, nullptr, En);

    hipMemsetAsync(S1, 0, (size_t)ND * sizeof(float), stream);
    k_spmm_atomic<true, false><<<gS, tb, 0, stream>>>(nrow, ncol, nwt, nullptr, out, S1, shuf, En);
    hipMemsetAsync(zneg, 0, (size_t)ND * sizeof(float), stream);
    k_spmm_atomic<false, false><<<gS, tb, 0, stream>>>(nrow, ncol, nwt, nullptr, S1, zneg, nullptr, En);
  }
}

// Round 10
// 694.365 us; speedup vs baseline: 2.5764x; 1.0730x over previous
//
#include <hip/hip_runtime.h>

#define DIMF 64
#define SCAN_TPB 256
#define SCAN_VPT 8
#define SCAN_CHUNK (SCAN_TPB * SCAN_VPT)   // 2048 elements per block

typedef unsigned long long u64;
typedef unsigned int u32;

// ============================ CSR build ============================

// L-graph histogram: ONE 64-bit atomic per edge packs {cnt:hi32, deg:lo32 fixed-point 2^-24}.
__global__ __launch_bounds__(256) void k_hist_pack(const int* __restrict__ row,
    const float* __restrict__ w, u64* __restrict__ pairs, int E) {
  for (int e = blockIdx.x * 256 + threadIdx.x; e < E; e += gridDim.x * 256) {
    u32 fx = (u32)__float2uint_rn(w[e] * 16777216.0f);   // w * 2^24
    atomicAdd(&pairs[row[e]], (1ULL << 32) | (u64)fx);
  }
}

// N-graph histogram: count only
__global__ __launch_bounds__(256) void k_hist_cnt(const int* __restrict__ row,
    int* __restrict__ cnt, int E) {
  for (int e = blockIdx.x * 256 + threadIdx.x; e < E; e += gridDim.x * 256)
    atomicAdd(&cnt[row[e]], 1);
}

// unpack pairs -> rpL (counts) and dis = deg>0 ? rsqrt(deg) : 0
__global__ __launch_bounds__(256) void k_unpack(const u64* __restrict__ pairs,
    int* __restrict__ rpL, float* __restrict__ dis, int n) {
  int i = blockIdx.x * 256 + threadIdx.x;
  if (i < n) {
    u64 p = pairs[i];
    rpL[i] = (int)(p >> 32);
    float d = (float)(u32)p * 5.9604644775390625e-8f;    // 2^-24
    dis[i] = (d > 0.f) ? rsqrtf(d) : 0.f;
  }
}

// ---- hierarchical exclusive scan ----
__global__ __launch_bounds__(SCAN_TPB) void k_scan1(int* __restrict__ a,
    int* __restrict__ partial, int n) {
  __shared__ int ts[SCAN_TPB];
  int base = blockIdx.x * SCAN_CHUNK + threadIdx.x * SCAN_VPT;
  int v[SCAN_VPT];
  int s = 0;
#pragma unroll
  for (int i = 0; i < SCAN_VPT; ++i) {
    int idx = base + i;
    v[i] = (idx < n) ? a[idx] : 0;
    s += v[i];
  }
  ts[threadIdx.x] = s;
  __syncthreads();
  for (int off = 1; off < SCAN_TPB; off <<= 1) {
    int t = (threadIdx.x >= off) ? ts[threadIdx.x - off] : 0;
    __syncthreads();
    ts[threadIdx.x] += t;
    __syncthreads();
  }
  int run = (threadIdx.x > 0) ? ts[threadIdx.x - 1] : 0;
#pragma unroll
  for (int i = 0; i < SCAN_VPT; ++i) {
    int idx = base + i;
    if (idx < n) a[idx] = run;
    run += v[i];
  }
  if (threadIdx.x == SCAN_TPB - 1) partial[blockIdx.x] = ts[SCAN_TPB - 1];
}

__global__ __launch_bounds__(1024) void k_scan2(int* __restrict__ partial, int nb) {
  __shared__ int ts[1024];
  int t = threadIdx.x;
  ts[t] = (t < nb) ? partial[t] : 0;
  __syncthreads();
  for (int off = 1; off < 1024; off <<= 1) {
    int v = (t >= off) ? ts[t - off] : 0;
    __syncthreads();
    ts[t] += v;
    __syncthreads();
  }
  if (t < nb) partial[t] = (t > 0) ? ts[t - 1] : 0;
}

__global__ __launch_bounds__(SCAN_TPB) void k_scan3(int* __restrict__ a,
    const int* __restrict__ partial, int n) {
  int add = partial[blockIdx.x];
  int base = blockIdx.x * SCAN_CHUNK + threadIdx.x;
#pragma unroll
  for (int i = 0; i < SCAN_VPT; ++i) {
    int idx = base + i * SCAN_TPB;
    if (idx < n) a[idx] += add;
  }
}

// XCD-partitioned CSR scatter: block group (blockIdx&7) handles rows
// [part*rpp, (part+1)*rpp). Under %8 round-robin block->XCD mapping all
// writes to a given cw line come from one XCD -> merge in its L2 ->
// ~8x fewer HBM sector writes. Correct under ANY block->XCD mapping.
// rowptr: exclusive starts on entry, SHIFTED ends on exit.
template <bool NORM>
__global__ __launch_bounds__(256) void k_permute_xcd(const int* __restrict__ row,
    const int* __restrict__ col, const float* __restrict__ w,
    const float* __restrict__ dis, int* __restrict__ rowptr,
    int2* __restrict__ cw, int E, int rpp) {
  int part = blockIdx.x & 7;
  int rlo = part * rpp;
  int rhi = rlo + rpp;
  int gb = blockIdx.x >> 3;
  int nb = gridDim.x >> 3;
  for (int e = gb * 256 + threadIdx.x; e < E; e += nb * 256) {
    int r = row[e];
    if (r >= rlo && r < rhi) {
      int c = col[e];
      float we = w[e];
      if (NORM) we *= dis[r] * dis[c];
      int p = atomicAdd(&rowptr[r], 1);
      cw[p] = make_int2(c, __float_as_int(we));
    }
  }
}

// ============================ SpMM kernels ============================

// one wave per row, lane = feature; 8-way edge unroll for MLP.
template <bool PERM>
__global__ __launch_bounds__(256) void k_spmm_csr(const int* __restrict__ rend,
    const int2* __restrict__ cw, const float* __restrict__ src,
    float* __restrict__ dst, const int* __restrict__ perm, int n) {
  int lane = threadIdx.x & 63;
  int wave = (blockIdx.x * 256 + threadIdx.x) >> 6;
  int nw = (gridDim.x * 256) >> 6;
  for (int r = wave; r < n; r += nw) {
    int s = (r > 0) ? rend[r - 1] : 0;
    int e = rend[r];
    float acc = 0.f;
    int j = s;
    for (; j + 7 < e; j += 8) {
      int2 q[8];
      float v[8];
#pragma unroll
      for (int k = 0; k < 8; ++k) q[k] = cw[j + k];
#pragma unroll
      for (int k = 0; k < 8; ++k) {
        int c = q[k].x;
        if (PERM) c = perm[c];
        v[k] = src[(size_t)c * DIMF + lane];
      }
#pragma unroll
      for (int k = 0; k < 8; ++k) acc += __int_as_float(q[k].y) * v[k];
    }
    for (; j < e; ++j) {
      int2 q = cw[j];
      int c = q.x;
      if (PERM) c = perm[c];
      acc += __int_as_float(q.y) * src[(size_t)c * DIMF + lane];
    }
    dst[(size_t)r * DIMF + lane] = acc;
  }
}

// L-level-2 SpMM fused with combine: out = a*x + b*s1 + c2*(A @ s1)
__global__ __launch_bounds__(256) void k_spmm_combine(const int* __restrict__ rend,
    const int2* __restrict__ cw, const float* __restrict__ s1,
    const float* __restrict__ x, const float* __restrict__ temp,
    float* __restrict__ out, int n) {
  float T0 = fmaxf(temp[0], 0.f);
  float T1 = fmaxf(temp[1], 0.f);
  float T2 = fmaxf(temp[2], 0.f);
  float c2 = (T0 + T2 - 2.f * T1) * 0.25f;
  float a = T1 + c2;
  float b = -((T1 - T0) + 2.f * c2);
  int lane = threadIdx.x & 63;
  int wave = (blockIdx.x * 256 + threadIdx.x) >> 6;
  int nw = (gridDim.x * 256) >> 6;
  for (int r = wave; r < n; r += nw) {
    int s = (r > 0) ? rend[r - 1] : 0;
    int e = rend[r];
    float acc = 0.f;
    int j = s;
    for (; j + 7 < e; j += 8) {
      int2 q[8];
      float v[8];
#pragma unroll
      for (int k = 0; k < 8; ++k) q[k] = cw[j + k];
#pragma unroll
      for (int k = 0; k < 8; ++k) v[k] = s1[(size_t)q[k].x * DIMF + lane];
#pragma unroll
      for (int k = 0; k < 8; ++k) acc += __int_as_float(q[k].y) * v[k];
    }
    for (; j < e; ++j) {
      int2 q = cw[j];
      acc += __int_as_float(q.y) * s1[(size_t)q.x * DIMF + lane];
    }
    size_t o = (size_t)r * DIMF + lane;
    out[o] = a * x[o] + b * s1[o] + c2 * acc;
  }
}

// dual-input SpMM (level 1): dst0[r] = sum w*src[c], dst1[r] = sum w*src[perm[c]]
__global__ __launch_bounds__(256) void k_spmm_dual(const int* __restrict__ rend,
    const int2* __restrict__ cw, const float* __restrict__ src,
    float* __restrict__ dst0, float* __restrict__ dst1,
    const int* __restrict__ perm, int n) {
  int lane = threadIdx.x & 63;
  int wave = (blockIdx.x * 256 + threadIdx.x) >> 6;
  int nw = (gridDim.x * 256) >> 6;
  for (int r = wave; r < n; r += nw) {
    int s = (r > 0) ? rend[r - 1] : 0;
    int e = rend[r];
    float acc0 = 0.f, acc1 = 0.f;
    int j = s;
    for (; j + 3 < e; j += 4) {
      int2 q[4];
      float v0[4], v1[4];
#pragma unroll
      for (int k = 0; k < 4; ++k) q[k] = cw[j + k];
#pragma unroll
      for (int k = 0; k < 4; ++k) {
        int c = q[k].x;
        int cp = perm[c];
        v0[k] = src[(size_t)c * DIMF + lane];
        v1[k] = src[(size_t)cp * DIMF + lane];
      }
#pragma unroll
      for (int k = 0; k < 4; ++k) {
        float wv = __int_as_float(q[k].y);
        acc0 += wv * v0[k];
        acc1 += wv * v1[k];
      }
    }
    for (; j < e; ++j) {
      int2 q = cw[j];
      float wv = __int_as_float(q.y);
      acc0 += wv * src[(size_t)q.x * DIMF + lane];
      acc1 += wv * src[(size_t)perm[q.x] * DIMF + lane];
    }
    dst0[(size_t)r * DIMF + lane] = acc0;
    dst1[(size_t)r * DIMF + lane] = acc1;
  }
}

// dual-src SpMM (level 2): dstA[r] = sum w*srcA[c], dstB[r] = sum w*srcB[c]
// shares rowptr/cw stream; same col index for both gathers.
__global__ __launch_bounds__(256) void k_spmm_dual2(const int* __restrict__ rend,
    const int2* __restrict__ cw, const float* __restrict__ srcA,
    const float* __restrict__ srcB, float* __restrict__ dstA,
    float* __restrict__ dstB, int n) {
  int lane = threadIdx.x & 63;
  int wave = (blockIdx.x * 256 + threadIdx.x) >> 6;
  int nw = (gridDim.x * 256) >> 6;
  for (int r = wave; r < n; r += nw) {
    int s = (r > 0) ? rend[r - 1] : 0;
    int e = rend[r];
    float accA = 0.f, accB = 0.f;
    int j = s;
    for (; j + 3 < e; j += 4) {
      int2 q[4];
      float vA[4], vB[4];
#pragma unroll
      for (int k = 0; k < 4; ++k) q[k] = cw[j + k];
#pragma unroll
      for (int k = 0; k < 4; ++k) {
        size_t off = (size_t)q[k].x * DIMF + lane;
        vA[k] = srcA[off];
        vB[k] = srcB[off];
      }
#pragma unroll
      for (int k = 0; k < 4; ++k) {
        float wv = __int_as_float(q[k].y);
        accA += wv * vA[k];
        accB += wv * vB[k];
      }
    }
    for (; j < e; ++j) {
      int2 q = cw[j];
      float wv = __int_as_float(q.y);
      size_t off = (size_t)q.x * DIMF + lane;
      accA += wv * srcA[off];
      accB += wv * srcB[off];
    }
    dstA[(size_t)r * DIMF + lane] = accA;
    dstB[(size_t)r * DIMF + lane] = accB;
  }
}

// ============================ atomic fallback path ============================

__global__ __launch_bounds__(256) void k_dis_fb(float* __restrict__ deg, int n) {
  int i = blockIdx.x * 256 + threadIdx.x;
  if (i < n) {
    float d = deg[i];
    deg[i] = (d > 0.f) ? rsqrtf(d) : 0.f;
  }
}

__global__ __launch_bounds__(256) void k_combine_fb(const float* __restrict__ x,
    const float* __restrict__ s1, const float* __restrict__ s2,
    const float* __restrict__ temp, float* __restrict__ out, int n4) {
  float T0 = fmaxf(temp[0], 0.f);
  float T1 = fmaxf(temp[1], 0.f);
  float T2 = fmaxf(temp[2], 0.f);
  float c2 = (T0 + T2 - 2.f * T1) * 0.25f;
  float a = T1 + c2;
  float b = -((T1 - T0) + 2.f * c2);
  const float4* x4 = (const float4*)x;
  const float4* a4 = (const float4*)s1;
  const float4* b4 = (const float4*)s2;
  float4* o4 = (float4*)out;
  for (int i = blockIdx.x * 256 + threadIdx.x; i < n4; i += gridDim.x * 256) {
    float4 xv = x4[i], sv = a4[i], tv = b4[i];
    float4 r;
    r.x = a * xv.x + b * sv.x + c2 * tv.x;
    r.y = a * xv.y + b * sv.y + c2 * tv.y;
    r.z = a * xv.z + b * sv.z + c2 * tv.z;
    r.w = a * xv.w + b * sv.w + c2 * tv.w;
    o4[i] = r;
  }
}

template <bool PERM, bool NORM>
__global__ __launch_bounds__(256) void k_spmm_atomic(const int* __restrict__ row,
    const int* __restrict__ col, const float* __restrict__ w,
    const float* __restrict__ dis, const float* __restrict__ src,
    float* __restrict__ dst, const int* __restrict__ perm, int E) {
  int lane = threadIdx.x & 63;
  int wave = (blockIdx.x * 256 + threadIdx.x) >> 6;
  int nwaves = (gridDim.x * 256) >> 6;
  for (int e = wave; e < E; e += nwaves) {
    int r = row[e];
    int c = col[e];
    float we = w[e];
    if (NORM) we *= dis[r] * dis[c];
    if (PERM) c = perm[c];
    float v = we * src[(size_t)c * DIMF + lane];
    atomicAdd(&dst[(size_t)r * DIMF + lane], v);
  }
}

__global__ __launch_bounds__(256) void k_deg_fb(const int* __restrict__ row,
    const float* __restrict__ ew, float* __restrict__ deg, int E) {
  for (int e = blockIdx.x * 256 + threadIdx.x; e < E; e += gridDim.x * 256)
    atomicAdd(&deg[row[e]], ew[e]);
}

// ============================ launch ============================

extern "C" void kernel_launch(void* const* d_in, const int* in_sizes, int n_in,
                              void* d_out, int out_size, void* d_ws, size_t ws_size,
                              hipStream_t stream) {
  const float* x    = (const float*)d_in[0];
  const int*   shuf = (const int*)d_in[1];
  const int*   eidx = (const int*)d_in[2];
  const float* ew   = (const float*)d_in[3];
  const int*   nidx = (const int*)d_in[4];
  const float* nwt  = (const float*)d_in[5];
  const float* temp = (const float*)d_in[6];

  const int ND = in_sizes[0];
  const int n  = ND / DIMF;
  const int E  = in_sizes[2] / 2;
  const int En = in_sizes[4] / 2;

  const int* erow = eidx;
  const int* ecol = eidx + E;
  const int* nrow = nidx;
  const int* ncol = nidx + En;

  float* out  = (float*)d_out;       // ND
  float* zpos = out + ND;            // ND
  float* zneg = zpos + ND;           // ND

  const int tb = 256;
  const int gE  = (E + tb - 1) / tb;
  const int gN  = (n + tb - 1) / tb;
  const int gS  = 2048;              // multiple of 8 (XCD partition)
  const int nbS = (n + SCAN_CHUNK - 1) / SCAN_CHUNK;
  const int rpp = (n + 7) / 8;       // rows per XCD partition

  // base ws: dis(n) + S1(ND) + rpL(n) + cwL(2E) + rpN(n) + cwN(2En) + partial(1024)
  size_t need  = sizeof(float) * ((size_t)3 * n + (size_t)ND
                                  + 2 * (size_t)E + 2 * (size_t)En + 1024);
  // extra ND for negmid buffer (enables level-2 dual fusion)
  size_t need2 = need + sizeof(float) * (size_t)ND;

  if (ws_size >= need && nbS <= 1024 && 2 * (size_t)E >= 2 * (size_t)n) {
    // ---------------- CSR path ----------------
    float* dis   = (float*)d_ws;          // n
    float* S1    = dis + n;               // ND
    int*   rpL   = (int*)(S1 + ND);       // n
    int2*  cwL   = (int2*)(rpL + n);      // E
    int*   rpN   = (int*)(cwL + E);       // n
    int2*  cwN   = (int2*)(rpN + n);      // En
    int*   partial = (int*)(cwN + En);    // 1024
    float* M1    = (float*)(partial + 1024); // ND (only if ws_size >= need2)
    u64*   pairs = (u64*)cwL;             // n u64, overlay (dead before permute)
    bool   dual2 = (ws_size >= need2);

    // histograms
    hipMemsetAsync(pairs, 0, (size_t)n * sizeof(u64), stream);
    hipMemsetAsync(rpN, 0, (size_t)n * sizeof(int), stream);
    k_hist_pack<<<gE, tb, 0, stream>>>(erow, ew, pairs, E);
    k_hist_cnt<<<gE, tb, 0, stream>>>(nrow, rpN, En);
    k_unpack<<<gN, tb, 0, stream>>>(pairs, rpL, dis, n);

    // exclusive scans
    k_scan1<<<nbS, SCAN_TPB, 0, stream>>>(rpL, partial, n);
    k_scan2<<<1, 1024, 0, stream>>>(partial, nbS);
    k_scan3<<<nbS, SCAN_TPB, 0, stream>>>(rpL, partial, n);
    k_scan1<<<nbS, SCAN_TPB, 0, stream>>>(rpN, partial, n);
    k_scan2<<<1, 1024, 0, stream>>>(partial, nbS);
    k_scan3<<<nbS, SCAN_TPB, 0, stream>>>(rpN, partial, n);

    // XCD-partitioned CSR scatter
    k_permute_xcd<true><<<gS, tb, 0, stream>>>(erow, ecol, ew, dis, rpL, cwL, E, rpp);
    k_permute_xcd<false><<<gS, tb, 0, stream>>>(nrow, ncol, nwt, nullptr, rpN, cwN, En, rpp);

    // Laplacian: S1 = Anorm@x ; out = a*x + b*S1 + c2*(Anorm@S1)  [fused]
    k_spmm_csr<false><<<gS, tb, 0, stream>>>(rpL, cwL, x, S1, nullptr, n);
    k_spmm_combine<<<gS, tb, 0, stream>>>(rpL, cwL, S1, x, temp, out, n);

    if (dual2) {
      // level-1 dual: S1 = Nmm(out), M1 = Nmm(out[shuf])
      k_spmm_dual<<<gS, tb, 0, stream>>>(rpN, cwN, out, S1, M1, shuf, n);
      // level-2 dual: zpos = Nmm(S1), zneg = Nmm(M1) in one pass
      k_spmm_dual2<<<gS, tb, 0, stream>>>(rpN, cwN, S1, M1, zpos, zneg, n);
    } else {
      // level-1 dual: S1 = Nmm(out), zpos = Nmm(out[shuf]) [neg-mid]
      k_spmm_dual<<<gS, tb, 0, stream>>>(rpN, cwN, out, S1, zpos, shuf, n);
      k_spmm_csr<false><<<gS, tb, 0, stream>>>(rpN, cwN, zpos, zneg, nullptr, n);
      k_spmm_csr<false><<<gS, tb, 0, stream>>>(rpN, cwN, S1, zpos, nullptr, n);
    }
  } else {
    // ---------------- proven atomic fallback ----------------
    float* dis = (float*)d_ws;
    float* S1  = dis + n;

    hipMemsetAsync(dis, 0, (size_t)n * sizeof(float), stream);
    k_deg_fb<<<gE, tb, 0, stream>>>(erow, ew, dis, E);
    k_dis_fb<<<gN, tb, 0, stream>>>(dis, n);

    hipMemsetAsync(S1, 0, (size_t)ND * sizeof(float), stream);
    k_spmm_atomic<false, true><<<gS, tb, 0, stream>>>(erow, ecol, ew, dis, x, S1, nullptr, E);
    hipMemsetAsync(zneg, 0, (size_t)ND * sizeof(float), stream);
    k_spmm_atomic<false, true><<<gS, tb, 0, stream>>>(erow, ecol, ew, dis, S1, zneg, nullptr, E);

    k_combine_fb<<<gS, tb, 0, stream>>>(x, S1, zneg, temp, out, ND / 4);

    hipMemsetAsync(S1, 0, (size_t)ND * sizeof(float), stream);
    k_spmm_atomic<false, false><<<gS, tb, 0, stream>>>(nrow, ncol, nwt, nullptr, out, S1, nullptr, En);
    hipMemsetAsync(zpos, 0, (size_t)ND * sizeof(float), stream);
    k_spmm_atomic<false, false><<<gS, tb, 0, stream>>>(nrow, ncol, nwt, nullptr, S1, zpos, nullptr, En);

    hipMemsetAsync(S1, 0, (size_t)ND * sizeof(float), stream);
    k_spmm_atomic<true, false><<<gS, tb, 0, stream>>>(nrow, ncol, nwt, nullptr, out, S1, shuf, En);
    hipMemsetAsync(zneg, 0, (size_t)ND * sizeof(float), stream);
    k_spmm_atomic<false, false><<<gS, tb, 0, stream>>>(nrow, ncol, nwt, nullptr, S1, zneg, nullptr, En);
  }
}